// Round 3
// baseline (2671.929 us; speedup 1.0000x reference)
//
#include <hip/hip_runtime.h>
#include <cstdint>

#define DIM 128

typedef unsigned short bf16t;

__device__ __forceinline__ unsigned short f2bf_bits(float f) {
    union { float f; uint32_t u; } x; x.f = f;
    uint32_t r = x.u + 0x7FFFu + ((x.u >> 16) & 1u);  // RN-even
    return (unsigned short)(r >> 16);
}

template <typename T> struct VecIO;
template <> struct VecIO<float> {
    static __device__ __forceinline__ float2 ld2(const float* p, size_t i) {
        return ((const float2*)p)[i];
    }
    static __device__ __forceinline__ void st2(float* p, size_t i, float2 v) {
        ((float2*)p)[i] = v;
    }
    static __device__ __forceinline__ void st1(float* p, float v) { *p = v; }
};
template <> struct VecIO<bf16t> {
    static __device__ __forceinline__ float2 ld2(const bf16t* p, size_t i) {
        uint32_t u = ((const uint32_t*)p)[i];
        union { uint32_t u; float f; } a, b;
        a.u = u << 16; b.u = u & 0xFFFF0000u;
        return make_float2(a.f, b.f);
    }
    static __device__ __forceinline__ void st2(bf16t* p, size_t i, float2 v) {
        uint32_t lo = f2bf_bits(v.x), hi = f2bf_bits(v.y);
        ((uint32_t*)p)[i] = lo | (hi << 16);
    }
    static __device__ __forceinline__ void st1(bf16t* p, float v) { *p = f2bf_bits(v); }
};

__device__ __forceinline__ float wave_reduce_sum(float v) {
    #pragma unroll
    for (int m = 32; m > 0; m >>= 1) v += __shfl_xor(v, m, 64);
    return v;
}

// ---------------- CSR build ----------------
__global__ __launch_bounds__(256) void k_hist(const int* __restrict__ rows, int E,
                                              int* __restrict__ counts) {
    int e = blockIdx.x * 256 + threadIdx.x;
    if (e < E) atomicAdd(&counts[rows[e] + 1], 1);
}

__global__ __launch_bounds__(256) void k_scan_tile(int* __restrict__ d, int n,
                                                   int* __restrict__ bsums) {
    __shared__ int sh[256];
    int t = threadIdx.x;
    int base = blockIdx.x * 1024 + t * 4;
    int v0 = (base + 0 < n) ? d[base + 0] : 0;
    int v1 = (base + 1 < n) ? d[base + 1] : 0;
    int v2 = (base + 2 < n) ? d[base + 2] : 0;
    int v3 = (base + 3 < n) ? d[base + 3] : 0;
    v1 += v0; v2 += v1; v3 += v2;
    sh[t] = v3;
    __syncthreads();
    #pragma unroll
    for (int off = 1; off < 256; off <<= 1) {
        int x = (t >= off) ? sh[t - off] : 0;
        __syncthreads();
        if (t >= off) sh[t] += x;
        __syncthreads();
    }
    int excl = (t > 0) ? sh[t - 1] : 0;
    v0 += excl; v1 += excl; v2 += excl; v3 += excl;
    if (base + 0 < n) d[base + 0] = v0;
    if (base + 1 < n) d[base + 1] = v1;
    if (base + 2 < n) d[base + 2] = v2;
    if (base + 3 < n) d[base + 3] = v3;
    if (t == 255 && bsums) bsums[blockIdx.x] = sh[255];
}

__global__ __launch_bounds__(256) void k_scan_add(int* __restrict__ d, int n,
                                                  const int* __restrict__ bsums) {
    if (blockIdx.x == 0) return;
    int add = bsums[blockIdx.x - 1];
    int base = blockIdx.x * 1024 + threadIdx.x * 4;
    #pragma unroll
    for (int i = 0; i < 4; ++i)
        if (base + i < n) d[base + i] += add;
}

__global__ __launch_bounds__(256) void k_scatter(const int* __restrict__ rows,
                                                 const int* __restrict__ cols,
                                                 const float* __restrict__ vals, int E,
                                                 int* __restrict__ cursor,
                                                 int* __restrict__ scol,
                                                 float* __restrict__ sval) {
    int e = blockIdx.x * 256 + threadIdx.x;
    if (e < E) {
        int r = rows[e];
        int p = atomicAdd(&cursor[r], 1);
        scol[p] = cols[e];
        sval[p] = vals[e];
    }
}

// ---------------- small prep ----------------
// w[k] = sum_d attn_mat[k][d] * attn[d]
__global__ __launch_bounds__(128) void k_attn_w(const float* __restrict__ attn_mat,
                                                const float* __restrict__ attn,
                                                float* __restrict__ w) {
    int k = threadIdx.x;
    float s = 0.f;
    for (int d = 0; d < DIM; ++d) s += attn_mat[k * DIM + d] * attn[d];
    w[k] = s;
}

// wtg[g][d][k] = gw[g][k][d]
__global__ __launch_bounds__(128) void k_twt(const float* __restrict__ gw,
                                             float* __restrict__ wtg) {
    int g = blockIdx.y, d = blockIdx.x, k = threadIdx.x;
    wtg[((size_t)g * DIM + d) * DIM + k] = gw[((size_t)g * DIM + k) * DIM + d];
}

template <typename T>
__global__ __launch_bounds__(256) void k_cvt(const float* __restrict__ src,
                                             T* __restrict__ dst, int n2) {
    int i = blockIdx.x * 256 + threadIdx.x;
    if (i < n2) VecIO<T>::st2(dst, i, ((const float2*)src)[i]);
}

// ---------------- channel attention + mix (+0.5*add) ----------------
template <typename TI>
__global__ __launch_bounds__(256) void k_attn_mix(const TI* __restrict__ e1,
                                                  const TI* __restrict__ e2,
                                                  const TI* __restrict__ e3,
                                                  const TI* __restrict__ add,
                                                  const float* __restrict__ w,
                                                  float* __restrict__ out, int n) {
    int wid = threadIdx.x >> 6, lane = threadIdx.x & 63;
    int u = blockIdx.x * 4 + wid;
    if (u >= n) return;
    size_t idx = (size_t)u * 64 + lane;
    float2 a = VecIO<TI>::ld2(e1, idx);
    float2 b = VecIO<TI>::ld2(e2, idx);
    float2 c = VecIO<TI>::ld2(e3, idx);
    float2 s = VecIO<TI>::ld2(add, idx);
    float2 wv = ((const float2*)w)[lane];
    float t1 = a.x * wv.x + a.y * wv.y;
    float t2 = b.x * wv.x + b.y * wv.y;
    float t3 = c.x * wv.x + c.y * wv.y;
    #pragma unroll
    for (int m = 32; m > 0; m >>= 1) {
        t1 += __shfl_xor(t1, m, 64);
        t2 += __shfl_xor(t2, m, 64);
        t3 += __shfl_xor(t3, m, 64);
    }
    float mx = fmaxf(t1, fmaxf(t2, t3));
    float x1 = __expf(t1 - mx), x2 = __expf(t2 - mx), x3 = __expf(t3 - mx);
    float inv = 1.f / (x1 + x2 + x3);
    x1 *= inv; x2 *= inv; x3 *= inv;
    float2 o;
    o.x = x1 * a.x + x2 * b.x + x3 * c.x + 0.5f * s.x;
    o.y = x1 * a.y + x2 * b.y + x3 * c.y + 0.5f * s.y;
    ((float2*)out)[idx] = o;
}

// ---------------- CSR spmm + fused l2-normalize accumulate ----------------
// y[r] = sum_j val_j * x[col_j];  acc[r] += y[r] / max(||y[r]||, 1e-12)
template <typename TI, typename TO, typename TA>
__global__ __launch_bounds__(256) void k_spmm(const int* __restrict__ off,
                                              const int* __restrict__ scol,
                                              const float* __restrict__ sval,
                                              const TI* __restrict__ x,
                                              TO* __restrict__ y,
                                              TA* __restrict__ acc, int n) {
    int wid = threadIdx.x >> 6, lane = threadIdx.x & 63;
    int r = blockIdx.x * 4 + wid;
    if (r >= n) return;
    int b = off[r], e = off[r + 1];
    float2 s = make_float2(0.f, 0.f);
    for (int j = b; j < e; ++j) {
        int c = scol[j];
        float v = sval[j];
        float2 xv = VecIO<TI>::ld2(x, (size_t)c * 64 + lane);
        s.x = fmaf(v, xv.x, s.x);
        s.y = fmaf(v, xv.y, s.y);
    }
    size_t idx = (size_t)r * 64 + lane;
    VecIO<TO>::st2(y, idx, s);
    float q = wave_reduce_sum(s.x * s.x + s.y * s.y);
    float rn = 1.f / fmaxf(sqrtf(q), 1e-12f);
    float2 av = VecIO<TA>::ld2(acc, idx);
    av.x = fmaf(s.x, rn, av.x);
    av.y = fmaf(s.y, rn, av.y);
    VecIO<TA>::st2(acc, idx, av);
}

// ---------------- gated GEMM: out = ue * sigmoid(ue @ W_g + b_g) ----------------
// wtg is W^T (per gate): wtg[d][k]. 16KB LDS user tile; W rows stream from L2.
template <typename T>
__global__ __launch_bounds__(256) void k_gate(const float* __restrict__ ue,
                                              const float* __restrict__ wtg,
                                              const float* __restrict__ gb,
                                              T* __restrict__ cbase,
                                              T* __restrict__ abase, int U) {
    __shared__ float us[32][DIM];
    int g = blockIdx.y;
    const float* wt = wtg + (size_t)g * DIM * DIM;
    int tid = threadIdx.x, d = tid & 127, rh = tid >> 7;
    float bv = gb[g * DIM + d];
    size_t UD = (size_t)U * DIM;
    T* cOut = cbase + (size_t)g * UD;
    T* aOut = abase + (size_t)g * UD;
    int row0 = blockIdx.x * 1024;
    int rowend = row0 + 1024; if (rowend > U) rowend = U;
    for (int r0 = row0; r0 < rowend; r0 += 32) {
        int nr = rowend - r0; if (nr > 32) nr = 32;
        const float4* src = (const float4*)(ue + (size_t)r0 * DIM);
        float4* dst = (float4*)us;
        for (int i = tid; i < nr * 32; i += 256) dst[i] = src[i];
        __syncthreads();
        float acc[16];
        #pragma unroll
        for (int rr = 0; rr < 16; ++rr) acc[rr] = 0.f;
        for (int k0 = 0; k0 < DIM; k0 += 4) {
            float4 w4 = *(const float4*)(wt + (size_t)d * DIM + k0);
            #pragma unroll
            for (int rr = 0; rr < 16; ++rr) {
                float4 u4 = *(const float4*)&us[rh * 16 + rr][k0];
                acc[rr] = fmaf(w4.x, u4.x, fmaf(w4.y, u4.y,
                          fmaf(w4.z, u4.z, fmaf(w4.w, u4.w, acc[rr]))));
            }
        }
        #pragma unroll
        for (int rr = 0; rr < 16; ++rr) {
            int r = r0 + rh * 16 + rr;
            if (r < rowend) {
                float sg = 1.f / (1.f + __expf(-(acc[rr] + bv)));
                float val = us[rh * 16 + rr][d] * sg;
                VecIO<T>::st1(cOut + (size_t)r * DIM + d, val);
                VecIO<T>::st1(aOut + (size_t)r * DIM + d, val);
            }
        }
        __syncthreads();
    }
}

// ---------------- orchestration ----------------
template <typename T>
static void run_all(const float* user_emb, const float* item_emb,
                    const float* gating_w, const float* gating_b,
                    const float* attn, const float* attn_mat,
                    const int* hs_row, const int* hs_col, const float* hs_val, int E_hs,
                    const int* hj_row, const int* hj_col, const float* hj_val, int E_hj,
                    const int* hp_row, const int* hp_col, const float* hp_val, int E_hp,
                    const int* r_row, const int* r_col, const float* r_val, int E_r,
                    int U, int I, float* out_user, float* out_item,
                    char* ws, hipStream_t stream) {
    const size_t UD = (size_t)U * DIM, ID = (size_t)I * DIM;
    char* p = ws;
    auto alloc = [&](size_t bytes) -> void* {
        void* r = (void*)p;
        p += (bytes + 255) & ~(size_t)255;
        return r;
    };
    T* S[5];
    for (int i = 0; i < 5; ++i) S[i] = (T*)alloc(UD * sizeof(T));  // contiguous: gate writes S[0..3]
    T* A = (T*)alloc(4 * UD * sizeof(T));                          // A1,A2,A3,AS contiguous
    T* itemA = (T*)alloc(ID * sizeof(T));
    T* itemB = (T*)alloc(ID * sizeof(T));
    float* wv  = (float*)alloc(DIM * sizeof(float));
    float* wtg = (float*)alloc(4 * DIM * DIM * sizeof(float));
    int* off_hs = (int*)alloc((size_t)(U + 1) * 4);
    int* off_hj = (int*)alloc((size_t)(U + 1) * 4);
    int* off_hp = (int*)alloc((size_t)(U + 1) * 4);
    int* off_ru = (int*)alloc((size_t)(U + 1) * 4);
    int* off_ri = (int*)alloc((size_t)(I + 1) * 4);
    int* cursor = (int*)alloc((size_t)(U + 1) * 4);
    int* bsums  = (int*)alloc(1024 * 4);
    int*   scol_hs = (int*)alloc((size_t)E_hs * 4);
    float* sval_hs = (float*)alloc((size_t)E_hs * 4);
    int*   scol_hj = (int*)alloc((size_t)E_hj * 4);
    float* sval_hj = (float*)alloc((size_t)E_hj * 4);
    int*   scol_hp = (int*)alloc((size_t)E_hp * 4);
    float* sval_hp = (float*)alloc((size_t)E_hp * 4);
    int*   scol_ru = (int*)alloc((size_t)E_r * 4);
    float* sval_ru = (float*)alloc((size_t)E_r * 4);
    int*   scol_ri = (int*)alloc((size_t)E_r * 4);
    float* sval_ri = (float*)alloc((size_t)E_r * 4);

    auto build = [&](const int* rows, const int* cols, const float* vals, int E, int N,
                     int* off, int* scol, float* sval) {
        hipMemsetAsync(off, 0, (size_t)(N + 1) * 4, stream);
        int gh = (E + 255) / 256;
        k_hist<<<gh, 256, 0, stream>>>(rows, E, off);
        int nb = (N + 1 + 1023) / 1024;
        k_scan_tile<<<nb, 256, 0, stream>>>(off, N + 1, bsums);
        k_scan_tile<<<1, 256, 0, stream>>>(bsums, nb, nullptr);
        k_scan_add<<<nb, 256, 0, stream>>>(off, N + 1, bsums);
        hipMemcpyAsync(cursor, off, (size_t)(N + 1) * 4, hipMemcpyDeviceToDevice, stream);
        k_scatter<<<gh, 256, 0, stream>>>(rows, cols, vals, E, cursor, scol, sval);
    };

    k_attn_w<<<1, 128, 0, stream>>>(attn_mat, attn, wv);
    dim3 tg(DIM, 4);
    k_twt<<<tg, 128, 0, stream>>>(gating_w, wtg);
    dim3 gg((U + 1023) / 1024, 4);
    k_gate<T><<<gg, 256, 0, stream>>>(user_emb, wtg, gating_b, S[0], A, U);
    k_cvt<T><<<(int)((ID / 2 + 255) / 256), 256, 0, stream>>>(item_emb, itemA, (int)(ID / 2));
    hipMemcpyAsync(out_item, item_emb, ID * sizeof(float), hipMemcpyDeviceToDevice, stream);

    build(hs_row, hs_col, hs_val, E_hs, U, off_hs, scol_hs, sval_hs);
    build(hj_row, hj_col, hj_val, E_hj, U, off_hj, scol_hj, sval_hj);
    build(hp_row, hp_col, hp_val, E_hp, U, off_hp, scol_hp, sval_hp);
    build(r_row, r_col, r_val, E_r, U, off_ru, scol_ru, sval_ru);   // R rows (U)
    build(r_col, r_row, r_val, E_r, I, off_ri, scol_ri, sval_ri);   // R^T rows (I)

    T *A1 = A, *A2 = A + UD, *A3 = A + 2 * UD, *AS = A + 3 * UD;
    T *c1 = S[0], *c2 = S[1], *c3 = S[2], *sp = S[3], *spare = S[4];
    T *itc = itemA, *itn = itemB;
    float* mixed = out_user;  // f32 scratch aliasing output region (fully rewritten later)
    int gbU = (U + 3) / 4, gbI = (I + 3) / 4;

    for (int layer = 0; layer < 2; ++layer) {
        k_attn_mix<T><<<gbU, 256, 0, stream>>>(c1, c2, c3, sp, wv, mixed, U);
        k_spmm<T, T, T><<<gbU, 256, 0, stream>>>(off_hs, scol_hs, sval_hs, c1, spare, A1, U);
        k_spmm<T, T, T><<<gbU, 256, 0, stream>>>(off_hj, scol_hj, sval_hj, c2, c1, A2, U);
        k_spmm<T, T, T><<<gbU, 256, 0, stream>>>(off_hp, scol_hp, sval_hp, c3, c2, A3, U);
        k_spmm<float, T, float><<<gbI, 256, 0, stream>>>(off_ri, scol_ri, sval_ri, mixed, itn, out_item, I);
        k_spmm<T, T, T><<<gbU, 256, 0, stream>>>(off_ru, scol_ru, sval_ru, itc, c3, AS, U);
        // rotate: (c1,c2,c3,sp,spare) <- (spare, c1, c2, c3, sp)  [buffers, not values]
        T* t0 = spare; T* t1 = c1; T* t2 = c2; T* t3 = c3; T* t4 = sp;
        c1 = t0; c2 = t1; c3 = t2; sp = t3; spare = t4;
        T* tt = itc; itc = itn; itn = tt;
    }
    k_attn_mix<T><<<gbU, 256, 0, stream>>>(A1, A2, A3, AS, wv, out_user, U);
}

extern "C" void kernel_launch(void* const* d_in, const int* in_sizes, int n_in,
                              void* d_out, int out_size, void* d_ws, size_t ws_size,
                              hipStream_t stream) {
    const float* user_emb = (const float*)d_in[0];
    const float* item_emb = (const float*)d_in[1];
    const float* gating_w = (const float*)d_in[2];
    const float* gating_b = (const float*)d_in[3];
    const float* attn     = (const float*)d_in[4];
    const float* attn_mat = (const float*)d_in[5];
    const int*   hs_row = (const int*)d_in[6];
    const int*   hs_col = (const int*)d_in[7];
    const float* hs_val = (const float*)d_in[8];
    const int*   hj_row = (const int*)d_in[9];
    const int*   hj_col = (const int*)d_in[10];
    const float* hj_val = (const float*)d_in[11];
    const int*   hp_row = (const int*)d_in[12];
    const int*   hp_col = (const int*)d_in[13];
    const float* hp_val = (const float*)d_in[14];
    const int*   r_row  = (const int*)d_in[15];
    const int*   r_col  = (const int*)d_in[16];
    const float* r_val  = (const float*)d_in[17];

    const int U = in_sizes[0] / DIM;
    const int I = in_sizes[1] / DIM;
    const int E_hs = in_sizes[6], E_hj = in_sizes[9], E_hp = in_sizes[12], E_r = in_sizes[15];
    const size_t UD = (size_t)U * DIM, ID = (size_t)I * DIM;

    float* out_user = (float*)d_out;
    float* out_item = out_user + UD;

    // footprint (256B-aligned per alloc; generous slack)
    size_t csr = 2 * ((size_t)E_hs + E_hj + E_hp + 2 * (size_t)E_r) * 4;
    size_t offs = 5 * (size_t)(U + 2) * 4 + (size_t)(I + 2) * 4 + 4096 + DIM * 4 +
                  4 * DIM * DIM * 4 + (1 << 16);
    size_t reqF = 9 * UD * 4 + 2 * ID * 4 + csr + offs;

    if (ws_size >= reqF) {
        run_all<float>(user_emb, item_emb, gating_w, gating_b, attn, attn_mat,
                       hs_row, hs_col, hs_val, E_hs, hj_row, hj_col, hj_val, E_hj,
                       hp_row, hp_col, hp_val, E_hp, r_row, r_col, r_val, E_r,
                       U, I, out_user, out_item, (char*)d_ws, stream);
    } else {
        run_all<bf16t>(user_emb, item_emb, gating_w, gating_b, attn, attn_mat,
                       hs_row, hs_col, hs_val, E_hs, hj_row, hj_col, hj_val, E_hj,
                       hp_row, hp_col, hp_val, E_hp, r_row, r_col, r_val, E_r,
                       U, I, out_user, out_item, (char*)d_ws, stream);
    }
}